// Round 1
// baseline (909.144 us; speedup 1.0000x reference)
//
#include <hip/hip_runtime.h>
#include <stdint.h>

#define NB 4096
#define NT 200
#define NE 64
// attention: 4E=256 -> 64 -> 32 -> 1 ; final MLP: 272 -> 256 -> 128 -> 1
//
// ABI (proven R2-R10): identity order, fp32 floats, int32 ints, FP32 output.
//
// R14: scalar-path weights (LDS-issue bound -> VALU bound).
//  - R13 post-mortem: 380us matches 98K ds_read_b128/CU at ~9cyc; VALU floor
//    is 82us. The broadcast weight reads on the LDS pipe were the binding
//    resource, not bank conflicts (14K conflict-cyc/CU = noise).
//  - Now: h1[j] = k.(A+C)[:,j] + (k*q).D[:,j] + biasj[j]. (A+C|D) is a
//    GLOBAL constant -> prep kernel transposes it into g_WC[64][128] once;
//    inner loop reads g_WC/att_w2/att_b2/att_wo via wave-uniform indices on
//    const-restrict pointers -> s_load (SMEM/constant cache), zero LDS.
//    L1 FMA count doubles (q un-folded) but 146us VALU floor << 380us LDS.
//  - LDS now 1.5KB; kq costs +64 VGPR -> ~190 VGPR, 2 waves/SIMD (VALU loop
//    saturates a SIMD from one wave; 2 covers s_load latency).
//  - din_mlp: 4 rows/block (1024 blocks, 4 blk/CU vs 1) + transposed LDS
//    activations (1 uniform b128/k instead of 4 b32).

__device__ float g_WC[64 * 128];   // [j][e]: e<64 -> (A+C)[e][j], e>=64 -> D[e-64][j]

// compile-time component access into a float4[16] register array
#define C4(v, i) (((i)&3)==0 ? v[(i)>>2].x : ((i)&3)==1 ? v[(i)>>2].y : \
                  ((i)&3)==2 ? v[(i)>>2].z : v[(i)>>2].w)

#define BF_STAGE(S)                                                        \
    {                                                                      \
        const bool hi = (j & (S)) != 0;                                    \
        _Pragma("unroll")                                                  \
        for (int i = 0; i < (S); ++i) {                                    \
            const float snd = hi ? C4(kvec, i) : C4(kvec, i + (S));        \
            const float rec = __shfl_xor(snd, (S), 64);                    \
            C4(kvec, i) = (hi ? C4(kvec, i + (S)) : C4(kvec, i)) + rec;    \
        }                                                                  \
    }

// ---------------------------------------------------------------------------
// Prep: transpose att_w1 columns into s_load-friendly rows.
// g_WC[j*128 + e]      = att_w1[e][j] + att_w1[128+e][j]   (k coefficient)
// g_WC[j*128 + 64 + e] = att_w1[192+e][j]                  (k*q coefficient)
// ---------------------------------------------------------------------------
__global__ void din_prep(const float* __restrict__ att_w1)
{
    const int i = blockIdx.x * 256 + threadIdx.x;   // 0..8191
    const int jo = i & 63;                          // output unit j (coalesced read)
    const int e  = i >> 6;                          // 0..127
    float v;
    if (e < 64)
        v = att_w1[(size_t)e * NE + jo] + att_w1[(size_t)(128 + e) * NE + jo];
    else
        v = att_w1[(size_t)(192 + (e - 64)) * NE + jo];
    g_WC[jo * 128 + e] = v;
}

struct __align__(16) SmemA {
    float q[64];
    float biasj[64];
    float ip[4 * 64];   // bias partials, later interest partials
    float red_a[4];
    float red_b[4];
};                       // 1568 B

__global__ __launch_bounds__(256, 2)
void din_attn(const int* __restrict__ target_item,
              const int* __restrict__ history_items,
              const int* __restrict__ history_mask,
              const int* __restrict__ sparse_features,
              const float* __restrict__ dense_features,
              const float* __restrict__ item_table,
              const float* __restrict__ user_table,
              const float* __restrict__ ctx_table,
              const float* __restrict__ att_w1,
              const float* __restrict__ att_b1,
              const float* __restrict__ att_w2,
              const float* __restrict__ att_b2,
              const float* __restrict__ att_wo,
              const float* __restrict__ att_bo,
              float* __restrict__ mlp_in)   // [NB][272]
{
    __shared__ SmemA sm;

    const int b   = blockIdx.x;
    const int tid = threadIdx.x;
    const int j   = tid & 63;
    const int wv  = tid >> 6;
    const int t   = tid;            // lane = history position
    const bool act = (t < NT);

    // ---- issue own-key loads FIRST (registers; overlaps all staging) ----
    const int hrow = history_items[(size_t)b * NT + (act ? t : NT - 1)];
    float4 kvec[16];
    {
        const float4* rp = (const float4*)(item_table + (size_t)hrow * NE);
#pragma unroll
        for (int i = 0; i < 16; ++i) kvec[i] = rp[i];
    }

    // ---- stage q ---------------------------------------------------------
    if (tid < NE) sm.q[tid] = item_table[(size_t)target_item[b] * NE + tid];
    __syncthreads();

    // ---- bias partials: biasj[j] = b1[j] + sum_e q_e*(B[e][j]-C[e][j]) ---
    {
        float pb = 0.f;
        for (int e = wv; e < NE; e += 4) {
            const float qe = sm.q[e];
            const float Bv = att_w1[(size_t)(64 + e)  * NE + j];
            const float Cv = att_w1[(size_t)(128 + e) * NE + j];
            pb += qe * (Bv - Cv);
        }
        sm.ip[wv * 64 + j] = pb;
    }
    __syncthreads();
    if (tid < NE)
        sm.biasj[tid] = att_b1[tid] + sm.ip[tid] + sm.ip[64 + tid] +
                        sm.ip[128 + tid] + sm.ip[192 + tid];
    __syncthreads();

    // ---- kq = k * q in registers (q broadcast from LDS, read once) ------
    float4 kq[16];
    {
        const float4* qv = (const float4*)sm.q;
#pragma unroll
        for (int i = 0; i < 16; ++i) {
            const float4 qq = qv[i];
            kq[i].x = kvec[i].x * qq.x;
            kq[i].y = kvec[i].y * qq.y;
            kq[i].z = kvec[i].z * qq.z;
            kq[i].w = kvec[i].w * qq.w;
        }
    }

    // ---- main loop: all weights via wave-uniform (s_load) paths ---------
    float h2[32];
#pragma unroll
    for (int o = 0; o < 32; ++o) h2[o] = 0.f;

    for (int jj = 0; jj < 64; ++jj) {
        const float* wrow = g_WC + jj * 128;        // uniform -> SMEM
        float a0 = 0.f, a1 = 0.f, a2 = 0.f, a3 = 0.f;
        float a4 = 0.f, a5 = 0.f, a6 = 0.f, a7 = 0.f;
#pragma unroll
        for (int e = 0; e < 64; e += 8) {
            a0 += wrow[e + 0] * C4(kvec, e + 0);
            a1 += wrow[e + 1] * C4(kvec, e + 1);
            a2 += wrow[e + 2] * C4(kvec, e + 2);
            a3 += wrow[e + 3] * C4(kvec, e + 3);
            a4 += wrow[e + 4] * C4(kvec, e + 4);
            a5 += wrow[e + 5] * C4(kvec, e + 5);
            a6 += wrow[e + 6] * C4(kvec, e + 6);
            a7 += wrow[e + 7] * C4(kvec, e + 7);
        }
#pragma unroll
        for (int e = 0; e < 64; e += 8) {
            a0 += wrow[64 + e + 0] * C4(kq, e + 0);
            a1 += wrow[64 + e + 1] * C4(kq, e + 1);
            a2 += wrow[64 + e + 2] * C4(kq, e + 2);
            a3 += wrow[64 + e + 3] * C4(kq, e + 3);
            a4 += wrow[64 + e + 4] * C4(kq, e + 4);
            a5 += wrow[64 + e + 5] * C4(kq, e + 5);
            a6 += wrow[64 + e + 6] * C4(kq, e + 6);
            a7 += wrow[64 + e + 7] * C4(kq, e + 7);
        }
        const float h1 = fmaxf((((a0 + a1) + (a2 + a3)) +
                                ((a4 + a5) + (a6 + a7))) + sm.biasj[jj], 0.f);

        const float* w2row = att_w2 + jj * 32;      // uniform -> SMEM
#pragma unroll
        for (int o = 0; o < 32; ++o) h2[o] += h1 * w2row[o];
    }

    // ---- L3 score per lane (b2/wo/bo via uniform s_load) ----------------
    float s0 = 0.f, s1 = 0.f;
#pragma unroll
    for (int o = 0; o < 32; o += 2) {
        s0 += fmaxf(h2[o]     + att_b2[o],     0.f) * att_wo[o];
        s1 += fmaxf(h2[o + 1] + att_b2[o + 1], 0.f) * att_wo[o + 1];
    }
    const float scr = s0 + s1 + att_bo[0];
    const int mk = act ? history_mask[(size_t)b * NT + t] : 0;
    const float v = act ? ((mk != 0) ? scr : -1e9f) : -INFINITY;

    // ---- softmax over 256 lanes (4-wave reduce) -------------------------
    float m = v;
#pragma unroll
    for (int s = 32; s; s >>= 1) m = fmaxf(m, __shfl_xor(m, s));
    if (j == 0) sm.red_a[wv] = m;
    __syncthreads();
    const float mx = fmaxf(fmaxf(sm.red_a[0], sm.red_a[1]),
                           fmaxf(sm.red_a[2], sm.red_a[3]));
    const float ex = __expf(v - mx);   // -inf -> 0
    float ssum = ex;
#pragma unroll
    for (int s = 32; s; s >>= 1) ssum += __shfl_xor(ssum, s);
    if (j == 0) sm.red_b[wv] = ssum;
    __syncthreads();
    const float total = sm.red_b[0] + sm.red_b[1] + sm.red_b[2] + sm.red_b[3];
    const float w = ex / total;        // softmax weight of this lane's t

    // ---- interest: scale own key row, butterfly transpose-reduce --------
#pragma unroll
    for (int i = 0; i < 64; ++i) C4(kvec, i) *= w;
    BF_STAGE(32)
    BF_STAGE(16)
    BF_STAGE(8)
    BF_STAGE(4)
    BF_STAGE(2)
    BF_STAGE(1)
    // lane j now holds this wave's partial interest for e = j
    sm.ip[wv * 64 + j] = kvec[0].x;
    __syncthreads();

    // ---- assemble mlp_in row [user, ctx, q, interest, dense] ------------
    float* row = mlp_in + (size_t)b * 272;
    if (tid < NE) {
        const float inter = sm.ip[tid] + sm.ip[64 + tid] +
                            sm.ip[128 + tid] + sm.ip[192 + tid];
        row[0 + tid]   = user_table[(size_t)sparse_features[b * 2 + 0] * NE + tid];
        row[64 + tid]  = ctx_table[(size_t)sparse_features[b * 2 + 1] * NE + tid];
        row[128 + tid] = sm.q[tid];
        row[192 + tid] = inter;
    } else if (tid >= 64 && tid < 80) {
        row[256 + (tid - 64)] = dense_features[(size_t)b * 16 + (tid - 64)];
    }
}

// ---------------------------------------------------------------------------
// Kernel 2: final MLP 272 -> 256 -> 128 -> 1, 4 rows/block (4 blocks/CU)
// ---------------------------------------------------------------------------
__global__ __launch_bounds__(256)
void din_mlp(const float* __restrict__ mlp_in,
             const float* __restrict__ w1,
             const float* __restrict__ b1,
             const float* __restrict__ w2,
             const float* __restrict__ b2,
             const float* __restrict__ ow,
             const float* __restrict__ ob,
             float* __restrict__ out)
{
    __shared__ float inT[272 * 4];      // [k][r] transposed -> 1 uniform b128/k
    __shared__ float h1T[256 * 4];      // [k][r]
    __shared__ float p2[2 * 4 * 128];
    __shared__ float h2_lds[4 * 128];

    const int b0  = blockIdx.x * 4;
    const int tid = threadIdx.x;

    for (int i = tid; i < 4 * 272; i += 256) {
        const int r = i / 272, c = i - 272 * r;
        inT[c * 4 + r] = mlp_in[(size_t)b0 * 272 + i];
    }
    __syncthreads();

    // layer 1: 272 -> 256 (thread = col, 4 rows in registers)
    {
        const float bias = b1[tid];
        float acc0 = bias, acc1 = bias, acc2 = bias, acc3 = bias;
        const float4* iT = (const float4*)inT;
#pragma unroll 2
        for (int k = 0; k < 272; ++k) {
            const float wv = w1[(size_t)k * 256 + tid];
            const float4 iv = iT[k];
            acc0 += iv.x * wv; acc1 += iv.y * wv;
            acc2 += iv.z * wv; acc3 += iv.w * wv;
        }
        float4 hv;
        hv.x = fmaxf(acc0, 0.f); hv.y = fmaxf(acc1, 0.f);
        hv.z = fmaxf(acc2, 0.f); hv.w = fmaxf(acc3, 0.f);
        ((float4*)h1T)[tid] = hv;
    }
    __syncthreads();

    // layer 2: 256 -> 128, split-K over two half-blocks
    {
        const int o = tid & 127, half = tid >> 7;
        float c0 = 0.f, c1 = 0.f, c2 = 0.f, c3 = 0.f;
        const float4* hT = (const float4*)h1T;
#pragma unroll 2
        for (int kk = 0; kk < 128; ++kk) {
            const int k = half * 128 + kk;
            const float wv = w2[(size_t)k * 128 + o];
            const float4 hv = hT[k];
            c0 += hv.x * wv; c1 += hv.y * wv;
            c2 += hv.z * wv; c3 += hv.w * wv;
        }
        p2[(half * 4 + 0) * 128 + o] = c0;
        p2[(half * 4 + 1) * 128 + o] = c1;
        p2[(half * 4 + 2) * 128 + o] = c2;
        p2[(half * 4 + 3) * 128 + o] = c3;
    }
    __syncthreads();
    if (tid < 128) {
        const float bias = b2[tid];
#pragma unroll
        for (int r = 0; r < 4; ++r)
            h2_lds[r * 128 + tid] =
                fmaxf(p2[r * 128 + tid] + p2[(4 + r) * 128 + tid] + bias, 0.f);
    }
    __syncthreads();

    // layer 3: 128 -> 1 (16 lanes per row)
    if (tid < 64) {
        const int r = tid >> 4, l = tid & 15;
        float a = 0.f;
#pragma unroll
        for (int kk = 0; kk < 8; ++kk) {
            const int k = l * 8 + kk;
            a += h2_lds[r * 128 + k] * ow[k];
        }
        a += __shfl_xor(a, 8, 16);
        a += __shfl_xor(a, 4, 16);
        a += __shfl_xor(a, 2, 16);
        a += __shfl_xor(a, 1, 16);
        if (l == 0) out[b0 + r] = a + ob[0];
    }
}

// ---------------------------------------------------------------------------
extern "C" void kernel_launch(void* const* d_in, const int* in_sizes, int n_in,
                              void* d_out, int out_size, void* d_ws, size_t ws_size,
                              hipStream_t stream)
{
    float* mlp_in = (float*)d_ws;   // 4096*272*4 = 4.46 MB

    din_prep<<<32, 256, 0, stream>>>((const float*)d_in[8]);   // att_w1

    din_attn<<<NB, 256, 0, stream>>>(
        (const int*)d_in[0],      // target_item
        (const int*)d_in[1],      // history_items
        (const int*)d_in[2],      // history_mask
        (const int*)d_in[3],      // sparse_features
        (const float*)d_in[4],    // dense_features
        (const float*)d_in[5],    // item_table
        (const float*)d_in[6],    // user_table
        (const float*)d_in[7],    // ctx_table
        (const float*)d_in[8],  (const float*)d_in[9],   // att_w1, att_b1
        (const float*)d_in[10], (const float*)d_in[11],  // att_w2, att_b2
        (const float*)d_in[12], (const float*)d_in[13],  // att_wo, att_bo
        mlp_in);

    din_mlp<<<NB / 16 * 4, 256, 0, stream>>>(
        mlp_in,
        (const float*)d_in[14], (const float*)d_in[15],  // mlp_w1, mlp_b1
        (const float*)d_in[16], (const float*)d_in[17],  // mlp_w2, mlp_b2
        (const float*)d_in[18], (const float*)d_in[19],  // out_w, out_b
        (float*)d_out);
}

// Round 2
// 486.238 us; speedup vs baseline: 1.8697x; 1.8697x over previous
//
#include <hip/hip_runtime.h>
#include <stdint.h>

#define NB 4096
#define NT 200
#define NE 64
// attention: 4E=256 -> 64 -> 32 -> 1 ; final MLP: 272 -> 256 -> 128 -> 1
//
// ABI (proven R2-R10): identity order, fp32 floats, int32 ints, FP32 output.
//
// R15: 2 history positions per lane (halve LDS-broadcast instrs per FMA).
//  - R13 post-mortem: LDS-issue bound. 25 LDS instr/jj/wave, 64 waves/CU
//    over the kernel -> ~100K LDS instrs/CU ~= 380us. VALU floor ~85us.
//  - R14 post-mortem: scalar-path weights spilled kvec/kq (VGPR=120 < 190
//    live) and serialized on s_load chains -> 772us. Reverted.
//  - Now: block = 128 threads, one batch. Lane l owns t=l and t=l+128.
//    Each weight broadcast (weffT row, w2 row) feeds TWO h1/h2 pipelines:
//    total waves halve -> LDS instr count halves -> ~190us predicted.
//  - Registers: k0(64)+k1(64)+h2a(32)+h2b(32)+temps ~ 230 <= 256 at
//    2 waves/SIMD (launch_bounds(128,2)); NO kq array this time.
//  - din_mlp: reverted to proven R13 version (16 rows/block); prep dropped.

// compile-time component access into a float4[16] register array
#define C4(v, i) (((i)&3)==0 ? v[(i)>>2].x : ((i)&3)==1 ? v[(i)>>2].y : \
                  ((i)&3)==2 ? v[(i)>>2].z : v[(i)>>2].w)

#define BF_STAGE(S)                                                        \
    {                                                                      \
        const bool hi = (j & (S)) != 0;                                    \
        _Pragma("unroll")                                                  \
        for (int i = 0; i < (S); ++i) {                                    \
            const float snd = hi ? C4(k0, i) : C4(k0, i + (S));            \
            const float rec = __shfl_xor(snd, (S), 64);                    \
            C4(k0, i) = (hi ? C4(k0, i + (S)) : C4(k0, i)) + rec;          \
        }                                                                  \
    }

struct __align__(16) SmemA {
    float weffT[64 * 72];   // [j][e], e padded 64->72 (288B rows, 16B-aligned)
    float w2[64 * 32];      // [j][o]
    float q[64];
    float biasj[64];
    float b2[32];
    float wo[32];
    float ip[2 * 64];       // bias partials, later interest partials
    float red_a[2];
    float red_b[2];
};                           // 27.9 KB -> 4 blocks/CU at 2 waves/SIMD

__global__ __launch_bounds__(128, 2)
void din_attn(const int* __restrict__ target_item,
              const int* __restrict__ history_items,
              const int* __restrict__ history_mask,
              const int* __restrict__ sparse_features,
              const float* __restrict__ dense_features,
              const float* __restrict__ item_table,
              const float* __restrict__ user_table,
              const float* __restrict__ ctx_table,
              const float* __restrict__ att_w1,
              const float* __restrict__ att_b1,
              const float* __restrict__ att_w2,
              const float* __restrict__ att_b2,
              const float* __restrict__ att_wo,
              const float* __restrict__ att_bo,
              float* __restrict__ mlp_in)   // [NB][272]
{
    __shared__ SmemA sm;

    const int b   = blockIdx.x;
    const int tid = threadIdx.x;    // 0..127
    const int j   = tid & 63;
    const int wv  = tid >> 6;       // 0..1
    const int t0  = tid;            // always < 200
    const int t1  = tid + 128;
    const bool act1 = (t1 < NT);

    // ---- issue own-key loads FIRST (registers; overlap all staging) -----
    const int hrow0 = history_items[(size_t)b * NT + t0];
    const int hrow1 = history_items[(size_t)b * NT + (act1 ? t1 : 0)];
    float4 k0[16], k1[16];
    {
        const float4* rp0 = (const float4*)(item_table + (size_t)hrow0 * NE);
        const float4* rp1 = (const float4*)(item_table + (size_t)hrow1 * NE);
#pragma unroll
        for (int i = 0; i < 16; ++i) { k0[i] = rp0[i]; k1[i] = rp1[i]; }
    }

    // ---- stage small shared data ----------------------------------------
    if (tid < NE) sm.q[tid] = item_table[(size_t)target_item[b] * NE + tid];
    for (int i = tid; i < 512; i += 128)
        ((float4*)sm.w2)[i] = ((const float4*)att_w2)[i];
    if (tid < 32) { sm.b2[tid] = att_b2[tid]; sm.wo[tid] = att_wo[tid]; }
    const float bo = att_bo[0];
    __syncthreads();

    // ---- W_eff^T[j][e] + bias partials (thread = (wv, j), 32 e's) -------
    // attn_in = [k, q, k-q, k*q] @ w1 factorizes (q row-constant):
    // h1[j] = relu( sum_e k_e*(w1[e,j]+w1[128+e,j]+q_e*w1[192+e,j])
    //              + b1[j] + sum_e q_e*(w1[64+e,j]-w1[128+e,j]) )
    {
        float pb = 0.f;
        for (int e = wv; e < NE; e += 2) {
            const float qe = sm.q[e];
            const float A  = att_w1[(size_t)(e)       * NE + j];
            const float Bv = att_w1[(size_t)(64 + e)  * NE + j];
            const float C  = att_w1[(size_t)(128 + e) * NE + j];
            const float D  = att_w1[(size_t)(192 + e) * NE + j];
            sm.weffT[j * 72 + e] = A + C + qe * D;
            pb += qe * (Bv - C);
        }
        sm.ip[wv * 64 + j] = pb;
    }
    __syncthreads();
    if (tid < NE)
        sm.biasj[tid] = att_b1[tid] + sm.ip[tid] + sm.ip[64 + tid];
    __syncthreads();

    // ---- main loop: each weight broadcast feeds BOTH t pipelines --------
    float h2a[32], h2b[32];
#pragma unroll
    for (int o = 0; o < 32; ++o) { h2a[o] = 0.f; h2b[o] = 0.f; }

    for (int jj = 0; jj < 64; ++jj) {
        const float4* wrow = (const float4*)(sm.weffT + jj * 72);  // broadcast
        float a0 = 0.f, a1 = 0.f, a2 = 0.f, a3 = 0.f;
        float b0 = 0.f, b1v = 0.f, b2v = 0.f, b3 = 0.f;
#pragma unroll
        for (int g = 0; g < 16; g += 4) {
            const float4 w0 = wrow[g + 0];
            const float4 w1 = wrow[g + 1];
            const float4 w2v = wrow[g + 2];
            const float4 w3 = wrow[g + 3];
            a0 += w0.x * k0[g + 0].x; b0 += w0.x * k1[g + 0].x;
            a0 += w0.y * k0[g + 0].y; b0 += w0.y * k1[g + 0].y;
            a0 += w0.z * k0[g + 0].z; b0 += w0.z * k1[g + 0].z;
            a0 += w0.w * k0[g + 0].w; b0 += w0.w * k1[g + 0].w;
            a1 += w1.x * k0[g + 1].x; b1v += w1.x * k1[g + 1].x;
            a1 += w1.y * k0[g + 1].y; b1v += w1.y * k1[g + 1].y;
            a1 += w1.z * k0[g + 1].z; b1v += w1.z * k1[g + 1].z;
            a1 += w1.w * k0[g + 1].w; b1v += w1.w * k1[g + 1].w;
            a2 += w2v.x * k0[g + 2].x; b2v += w2v.x * k1[g + 2].x;
            a2 += w2v.y * k0[g + 2].y; b2v += w2v.y * k1[g + 2].y;
            a2 += w2v.z * k0[g + 2].z; b2v += w2v.z * k1[g + 2].z;
            a2 += w2v.w * k0[g + 2].w; b2v += w2v.w * k1[g + 2].w;
            a3 += w3.x * k0[g + 3].x; b3 += w3.x * k1[g + 3].x;
            a3 += w3.y * k0[g + 3].y; b3 += w3.y * k1[g + 3].y;
            a3 += w3.z * k0[g + 3].z; b3 += w3.z * k1[g + 3].z;
            a3 += w3.w * k0[g + 3].w; b3 += w3.w * k1[g + 3].w;
        }
        const float bias = sm.biasj[jj];
        const float h1a = fmaxf(((a0 + a1) + (a2 + a3)) + bias, 0.f);
        const float h1b = fmaxf(((b0 + b1v) + (b2v + b3)) + bias, 0.f);

        const float4* w2row = (const float4*)(sm.w2 + jj * 32);    // broadcast
#pragma unroll
        for (int o4 = 0; o4 < 8; ++o4) {
            const float4 ww = w2row[o4];
            h2a[4 * o4 + 0] += h1a * ww.x;  h2b[4 * o4 + 0] += h1b * ww.x;
            h2a[4 * o4 + 1] += h1a * ww.y;  h2b[4 * o4 + 1] += h1b * ww.y;
            h2a[4 * o4 + 2] += h1a * ww.z;  h2b[4 * o4 + 2] += h1b * ww.z;
            h2a[4 * o4 + 3] += h1a * ww.w;  h2b[4 * o4 + 3] += h1b * ww.w;
        }
    }

    // ---- L3 scores for both t's -----------------------------------------
    float sa = 0.f, sb = 0.f;
#pragma unroll
    for (int o = 0; o < 32; ++o) {
        const float bb = sm.b2[o], wwo = sm.wo[o];
        sa += fmaxf(h2a[o] + bb, 0.f) * wwo;
        sb += fmaxf(h2b[o] + bb, 0.f) * wwo;
    }
    const float scr0 = sa + bo;
    const float scr1 = sb + bo;
    const int mk0 = history_mask[(size_t)b * NT + t0];
    const int mk1 = act1 ? history_mask[(size_t)b * NT + t1] : 0;
    const float v0 = (mk0 != 0) ? scr0 : -1e9f;
    const float v1 = act1 ? ((mk1 != 0) ? scr1 : -1e9f) : -INFINITY;

    // ---- softmax over 256 slots (2 waves x 2 per lane) ------------------
    float m = fmaxf(v0, v1);
#pragma unroll
    for (int s = 32; s; s >>= 1) m = fmaxf(m, __shfl_xor(m, s));
    if (j == 0) sm.red_a[wv] = m;
    __syncthreads();
    const float mx = fmaxf(sm.red_a[0], sm.red_a[1]);
    const float ex0 = __expf(v0 - mx);   // -inf -> 0
    const float ex1 = __expf(v1 - mx);
    float ssum = ex0 + ex1;
#pragma unroll
    for (int s = 32; s; s >>= 1) ssum += __shfl_xor(ssum, s);
    if (j == 0) sm.red_b[wv] = ssum;
    __syncthreads();
    const float total = sm.red_b[0] + sm.red_b[1];
    const float w0s = ex0 / total;
    const float w1s = ex1 / total;

    // ---- interest: combine own 2 rows, butterfly transpose-reduce -------
#pragma unroll
    for (int i = 0; i < 64; ++i)
        C4(k0, i) = C4(k0, i) * w0s + C4(k1, i) * w1s;
    BF_STAGE(32)
    BF_STAGE(16)
    BF_STAGE(8)
    BF_STAGE(4)
    BF_STAGE(2)
    BF_STAGE(1)
    // lane j now holds this wave's partial interest for e = j
    sm.ip[wv * 64 + j] = k0[0].x;
    __syncthreads();

    // ---- assemble mlp_in row [user, ctx, q, interest, dense] ------------
    float* row = mlp_in + (size_t)b * 272;
    if (tid < NE) {
        const float inter = sm.ip[tid] + sm.ip[64 + tid];
        row[0 + tid]   = user_table[(size_t)sparse_features[b * 2 + 0] * NE + tid];
        row[64 + tid]  = ctx_table[(size_t)sparse_features[b * 2 + 1] * NE + tid];
        row[128 + tid] = sm.q[tid];
        row[192 + tid] = inter;
    } else if (tid >= 64 && tid < 80) {
        row[256 + (tid - 64)] = dense_features[(size_t)b * 16 + (tid - 64)];
    }
}

// ---------------------------------------------------------------------------
// Kernel 2: final MLP 272 -> 256 -> 128 -> 1, 16 rows/block (weights x16 reuse)
// (R13 version, proven)
// ---------------------------------------------------------------------------
__global__ __launch_bounds__(256)
void din_mlp(const float* __restrict__ mlp_in,
             const float* __restrict__ w1,
             const float* __restrict__ b1,
             const float* __restrict__ w2,
             const float* __restrict__ b2,
             const float* __restrict__ ow,
             const float* __restrict__ ob,
             float* __restrict__ out)
{
    __shared__ float in_lds[16 * 272];
    __shared__ float h1_lds[16 * 256];
    __shared__ float p2_lds[2 * 16 * 128];
    __shared__ float h2_lds[16 * 128];

    const int b0  = blockIdx.x * 16;
    const int tid = threadIdx.x;

    for (int i = tid; i < 16 * 272; i += 256)
        in_lds[i] = mlp_in[(size_t)b0 * 272 + i];
    __syncthreads();

    // layer 1: 272 -> 256 (thread = col, 16 rows in registers)
    {
        float acc[16];
        const float bias = b1[tid];
#pragma unroll
        for (int r = 0; r < 16; ++r) acc[r] = bias;
        for (int k = 0; k < 272; ++k) {
            const float wv = w1[(size_t)k * 256 + tid];
#pragma unroll
            for (int r = 0; r < 16; ++r) acc[r] += in_lds[r * 272 + k] * wv;
        }
#pragma unroll
        for (int r = 0; r < 16; ++r) h1_lds[r * 256 + tid] = fmaxf(acc[r], 0.f);
    }
    __syncthreads();

    // layer 2: 256 -> 128, split-K over two half-blocks
    {
        const int o = tid & 127, half = tid >> 7;
        float acc[16];
#pragma unroll
        for (int r = 0; r < 16; ++r) acc[r] = 0.f;
        for (int kk = 0; kk < 128; ++kk) {
            const int k = half * 128 + kk;
            const float wv = w2[(size_t)k * 128 + o];
#pragma unroll
            for (int r = 0; r < 16; ++r) acc[r] += h1_lds[r * 256 + k] * wv;
        }
#pragma unroll
        for (int r = 0; r < 16; ++r) p2_lds[(half * 16 + r) * 128 + o] = acc[r];
    }
    __syncthreads();
    if (tid < 128) {
        const float bias = b2[tid];
#pragma unroll
        for (int r = 0; r < 16; ++r)
            h2_lds[r * 128 + tid] =
                fmaxf(p2_lds[r * 128 + tid] + p2_lds[(16 + r) * 128 + tid] + bias, 0.f);
    }
    __syncthreads();

    // layer 3: 128 -> 1 (16 lanes per row)
    {
        const int r = tid >> 4, l = tid & 15;
        float a = 0.f;
#pragma unroll
        for (int kk = 0; kk < 8; ++kk) {
            const int k = l * 8 + kk;
            a += h2_lds[r * 128 + k] * ow[k];
        }
        a += __shfl_xor(a, 8, 16);
        a += __shfl_xor(a, 4, 16);
        a += __shfl_xor(a, 2, 16);
        a += __shfl_xor(a, 1, 16);
        if (l == 0) out[b0 + r] = a + ob[0];
    }
}

// ---------------------------------------------------------------------------
extern "C" void kernel_launch(void* const* d_in, const int* in_sizes, int n_in,
                              void* d_out, int out_size, void* d_ws, size_t ws_size,
                              hipStream_t stream)
{
    float* mlp_in = (float*)d_ws;   // 4096*272*4 = 4.46 MB

    din_attn<<<NB, 128, 0, stream>>>(
        (const int*)d_in[0],      // target_item
        (const int*)d_in[1],      // history_items
        (const int*)d_in[2],      // history_mask
        (const int*)d_in[3],      // sparse_features
        (const float*)d_in[4],    // dense_features
        (const float*)d_in[5],    // item_table
        (const float*)d_in[6],    // user_table
        (const float*)d_in[7],    // ctx_table
        (const float*)d_in[8],  (const float*)d_in[9],   // att_w1, att_b1
        (const float*)d_in[10], (const float*)d_in[11],  // att_w2, att_b2
        (const float*)d_in[12], (const float*)d_in[13],  // att_wo, att_bo
        mlp_in);

    din_mlp<<<NB / 16, 256, 0, stream>>>(
        mlp_in,
        (const float*)d_in[14], (const float*)d_in[15],  // mlp_w1, mlp_b1
        (const float*)d_in[16], (const float*)d_in[17],  // mlp_w2, mlp_b2
        (const float*)d_in[18], (const float*)d_in[19],  // out_w, out_b
        (float*)d_out);
}